// Round 16
// baseline (165.691 us; speedup 1.0000x reference)
//
#include <hip/hip_runtime.h>
#include <hip/hip_bf16.h>

// B=2, S=2048, D=1024, H=8, HD=128, RANK=4.
// Device I/O buffers are FP32 (per reference dtypes).
// Internal pipeline: convert to bf16 in d_ws, bf16 MFMA with fp32 accum.
// V is produced TRANSPOSED by the QKV GEMM (operand swap). Flash attention
// (champion config, R14/R15): swapped QK^T 32x32x16, in-register softmax,
// KVBLK=32, dbuf K/V, 4-wave blocks (QBLK=128), z=4, free register alloc
// (124 VGPR <= 128 cliff), XCD swizzle everywhere. This round: lora_down
// fused into cvt (one fewer launch), attn_merge thread-coarsened x2.

typedef __bf16 bf8_t __attribute__((ext_vector_type(8)));
typedef float f32x4 __attribute__((ext_vector_type(4)));
typedef float f32x16 __attribute__((ext_vector_type(16)));
typedef unsigned u32x4 __attribute__((ext_vector_type(4)));

#define MFMA16(a, b, c) __builtin_amdgcn_mfma_f32_16x16x32_bf16((a), (b), (c), 0, 0, 0)
#define MFMA32(a, b, c) __builtin_amdgcn_mfma_f32_32x32x16_bf16((a), (b), (c), 0, 0, 0)

__device__ __forceinline__ void gload_lds16(const void* g, void* l) {
  __builtin_amdgcn_global_load_lds(
      (const __attribute__((address_space(1))) void*)g,
      (__attribute__((address_space(3))) void*)l, 16, 0, 0);
}

__device__ __forceinline__ unsigned pk2(float a, float b) {
  unsigned short ua = __builtin_bit_cast(unsigned short, (__bf16)a);
  unsigned short ub = __builtin_bit_cast(unsigned short, (__bf16)b);
  return (unsigned)ua | ((unsigned)ub << 16);
}

__device__ __forceinline__ float fmax3(float a, float b, float c) {
  return fmaxf(fmaxf(a, b), c);  // clang fuses to v_max3_f32
}

// ---------------------------------------------------------------------------
// Kernel 0: fp32 -> bf16 conversion (y=0..4: hidden_states, Wq,Wk,Wv,Wo)
// + fused LoRA-down (y==5): tmp[s][r] = sum_d control[s][d]*down[r][d].
// ---------------------------------------------------------------------------
__global__ __launch_bounds__(256) void cvt6_k(
    const float* __restrict__ s0, const float* __restrict__ s1,
    const float* __restrict__ s2, const float* __restrict__ s3,
    const float* __restrict__ s4, __bf16* __restrict__ d0,
    __bf16* __restrict__ d1, __bf16* __restrict__ d2, __bf16* __restrict__ d3,
    __bf16* __restrict__ d4, const float* __restrict__ ctrl,
    const float* __restrict__ down, float* __restrict__ tmp) {
  const int which = blockIdx.y;
  if (which == 5) {
    // LoRA down: 1024 x-blocks x 4 waves = 4096 rows
    if (blockIdx.x >= 1024) return;
    const int tid = threadIdx.x, wave = tid >> 6, lane = tid & 63;
    const int s = blockIdx.x * 4 + wave;
    const float* cp = ctrl + (size_t)s * 1024 + lane * 16;
    float4 c[4];
#pragma unroll
    for (int i = 0; i < 4; ++i) c[i] = *(const float4*)(cp + i * 4);
#pragma unroll
    for (int r = 0; r < 4; ++r) {
      const float* dp = down + r * 1024 + lane * 16;
      float acc = 0.f;
#pragma unroll
      for (int i = 0; i < 4; ++i) {
        float4 dv = *(const float4*)(dp + i * 4);
        acc += c[i].x * dv.x + c[i].y * dv.y + c[i].z * dv.z + c[i].w * dv.w;
      }
      for (int off = 32; off > 0; off >>= 1) acc += __shfl_xor(acc, off);
      if (lane == 0) tmp[s * 4 + r] = acc;
    }
    return;
  }
  const float* s = (which == 0) ? s0 : (which == 1) ? s1 : (which == 2) ? s2
                   : (which == 3) ? s3 : s4;
  __bf16* d = (which == 0) ? d0 : (which == 1) ? d1 : (which == 2) ? d2
              : (which == 3) ? d3 : d4;
  const int n = (which == 0) ? (4096 * 1024) : (1024 * 1024);
  const int i = (blockIdx.x * 256 + threadIdx.x) * 8;
  if (i >= n) return;
  float4 a = *(const float4*)(s + i);
  float4 b = *(const float4*)(s + i + 4);
  bf8_t r;
  r[0] = (__bf16)a.x; r[1] = (__bf16)a.y; r[2] = (__bf16)a.z; r[3] = (__bf16)a.w;
  r[4] = (__bf16)b.x; r[5] = (__bf16)b.y; r[6] = (__bf16)b.z; r[7] = (__bf16)b.w;
  *(bf8_t*)(d + i) = r;
}

// ---------------------------------------------------------------------------
// GEMM tile body, templated on per-wave M-fragments MR (tile = MR*32 x 128).
// ---------------------------------------------------------------------------
template <int MR>
__device__ __forceinline__ void gemm_tile(const __bf16* __restrict__ Abase,
                                          const __bf16* __restrict__ Wbase,
                                          int K, __bf16* sA, __bf16* sB,
                                          f32x4 acc[MR][4]) {
  const int tid = threadIdx.x;
  const int wave = tid >> 6, lane = tid & 63;
  const int wr = (wave >> 1) * (MR * 16), wc = (wave & 1) * 64;
  const int lrow = lane >> 3, lchunk = lane & 7;

  for (int m = 0; m < MR; ++m)
    for (int n = 0; n < 4; ++n)
      acc[m][n] = f32x4{0.f, 0.f, 0.f, 0.f};

  for (int k0 = 0; k0 < K; k0 += 64) {
    for (int i = 0; i < MR; ++i) {
      const int rbase = i * 32 + wave * 8;
      gload_lds16(Abase + (size_t)(rbase + lrow) * K + k0 + lchunk * 8,
                  sA + rbase * 64);
    }
    for (int i = 0; i < 4; ++i) {
      const int rbase = i * 32 + wave * 8;
      gload_lds16(Wbase + (size_t)(rbase + lrow) * K + k0 + lchunk * 8,
                  sB + rbase * 64);
    }
    __syncthreads();

    for (int kk = 0; kk < 2; ++kk) {
      bf8_t af[MR], bfr[4];
      const int koff = kk * 32 + (lane >> 4) * 8;
      for (int m = 0; m < MR; ++m)
        af[m] = *(const bf8_t*)&sA[(wr + m * 16 + (lane & 15)) * 64 + koff];
      for (int n = 0; n < 4; ++n)
        bfr[n] = *(const bf8_t*)&sB[(wc + n * 16 + (lane & 15)) * 64 + koff];
      for (int m = 0; m < MR; ++m)
        for (int n = 0; n < 4; ++n)
          acc[m][n] = MFMA16(af[m], bfr[n], acc[m][n]);
    }
    __syncthreads();
  }
}

// ---------------------------------------------------------------------------
// Kernel 1: QKV projections. z==0/1: C = X.W^T; z==2: operands swapped so the
// output IS V^T: Vt[h*128+d][b*2048+s] (row-major [1024][4096]).
// T1 XCD swizzle: panel index = lin&7 = XCD owner (weights L2-resident).
// ---------------------------------------------------------------------------
__global__ __launch_bounds__(256) void gemm_qkv_k(
    const __bf16* __restrict__ X, const __bf16* __restrict__ Wq,
    const __bf16* __restrict__ Wk, const __bf16* __restrict__ Wv,
    __bf16* __restrict__ Qb, __bf16* __restrict__ Kb, __bf16* __restrict__ Vtb) {
  __shared__ __bf16 sA[128 * 64];
  __shared__ __bf16 sB[128 * 64];
  const int lin = blockIdx.x + 8 * (blockIdx.y + 32 * blockIdx.z);
  const int p8 = lin & 7;
  const int rest = lin >> 3;
  const int p32 = rest & 31;
  const int z = rest >> 5;
  const int K = 1024;
  int rowT, colT, Nout;
  const __bf16 *Abase, *Wbase;
  __bf16* C;
  if (z == 2) {
    rowT = p8; colT = p32; Nout = 4096;
    Abase = Wv + (size_t)rowT * 128 * K;
    Wbase = X + (size_t)colT * 128 * K;
    C = Vtb;
  } else {
    rowT = p32; colT = p8; Nout = 1024;
    Abase = X + (size_t)rowT * 128 * K;
    Wbase = ((z == 0) ? Wq : Wk) + (size_t)colT * 128 * K;
    C = (z == 0) ? Qb : Kb;
  }
  f32x4 acc[4][4];
  gemm_tile<4>(Abase, Wbase, K, sA, sB, acc);

  const int lane = threadIdx.x & 63, wave = threadIdx.x >> 6;
  const int wr = (wave >> 1) * 64, wc = (wave & 1) * 64;
  const int row0 = rowT * 128 + wr + (lane >> 4) * 4;
  const int col0 = colT * 128 + wc + (lane & 15);
  for (int m = 0; m < 4; ++m)
    for (int n = 0; n < 4; ++n)
      for (int j = 0; j < 4; ++j)
        C[(size_t)(row0 + m * 16 + j) * Nout + col0 + n * 16] = (__bf16)acc[m][n][j];
}

// ---------------------------------------------------------------------------
// Kernel 3: flash attention partial pass. 4-wave blocks (QBLK=128) sharing
// DOUBLE-buffered K/V tiles; KVBLK=32; z=4 kv-quarters; NO register cap
// (124 VGPR <= 128 cliff). grid 1024 blocks x 256 thr = 4 blocks/CU.
// XCD swizzle: xcd = lin&7 owns bh pair.
// ---------------------------------------------------------------------------
__global__ __launch_bounds__(256) void flash_attn_k(
    const __bf16* __restrict__ Qg, const __bf16* __restrict__ Kg,
    const __bf16* __restrict__ Vtg, __bf16* __restrict__ Op,
    float* __restrict__ ml) {
  const int S = 2048, D = 1024;
  const int NT = 16;  // KVBLK=32 tiles per kv-quarter
  __shared__ __bf16 sK[2][32 * 128];
  __shared__ __bf16 sVt[2][128 * 32];
  __shared__ float sW[4][32];

  const int lin = blockIdx.x + 16 * (blockIdx.y + 16 * blockIdx.z);
  const int bh = (lin & 7) * 2 + ((lin >> 9) & 1);
  const int qt = (lin >> 3) & 15;
  const int z = (lin >> 7) & 3;

  const int b = bh >> 3, h = bh & 7;
  const int tid = threadIdx.x, wave = tid >> 6, lane = tid & 63;
  const int l31 = lane & 31, hi = lane >> 5;
  const size_t base = (size_t)b * S * D + (size_t)h * 128;
  const size_t vtbase = (size_t)h * 128 * 4096 + (size_t)b * 2048;
  const int q0 = qt * 128 + wave * 32;
  const int kvofs = z * 512;

  // Q as B-fragments, pre-scaled by (1/sqrt(128))*log2(e) (exp2 domain).
  bf8_t qf[8];
  {
    const float c = 0.08838834764831845f * 1.4426950408889634f;
    const __bf16* qp = Qg + base + (size_t)(q0 + l31) * D + hi * 8;
#pragma unroll
    for (int dc = 0; dc < 8; ++dc) {
      bf8_t v = *(const bf8_t*)(qp + dc * 16);
#pragma unroll
      for (int j = 0; j < 8; ++j) v[j] = (__bf16)((float)v[j] * c);
      qf[dc] = v;
    }
  }

  f32x16 accO[4];
#pragma unroll
  for (int db = 0; db < 4; ++db)
#pragma unroll
    for (int j = 0; j < 16; ++j) accO[db][j] = 0.f;
  float m_ = -1e30f, l_ = 0.f;  // l_ is PER-HALF; cross-half reduce at end

  auto stageK = [&](int buf, int kv) {
#pragma unroll
    for (int i = 0; i < 2; ++i) {
      const int r = wave * 8 + i * 4 + (lane >> 4);
      const int gc = (lane & 15) ^ (r & 7);
      gload_lds16(Kg + base + (size_t)(kvofs + kv + r) * D + gc * 8,
                  &sK[buf][(wave * 8 + i * 4) * 128]);
    }
  };
  auto stageV = [&](int buf, int kv) {
#pragma unroll
    for (int i = 0; i < 2; ++i) {
      const int d = wave * 32 + i * 16 + (lane >> 2);
      const int gc = (lane & 3) ^ ((d >> 1) & 3);
      gload_lds16(Vtg + vtbase + (size_t)d * 4096 + kvofs + kv + gc * 8,
                  &sVt[buf][(wave * 32 + i * 16) * 32]);
    }
  };

  stageK(0, 0);
  stageV(0, 0);

  for (int t = 0; t < NT; ++t) {
    const int cur = t & 1;
    __syncthreads();  // drains DMA for buf[cur]; guards buf[cur^1] reuse
    if (t < NT - 1) {
      stageK(cur ^ 1, (t + 1) * 32);
      stageV(cur ^ 1, (t + 1) * 32);
    }

    // QK^T swapped: accS holds S[k][q]; q = l31, k = (r&3)+8*(r>>2)+4*hi.
    f32x16 accS;
#pragma unroll
    for (int j = 0; j < 16; ++j) accS[j] = 0.f;
    const __bf16* kb_ = sK[cur];
    const int kr = l31;
    __builtin_amdgcn_s_setprio(1);
#pragma unroll
    for (int dc = 0; dc < 8; ++dc) {
      bf8_t a = *(const bf8_t*)&kb_[kr * 128 + ((2 * dc + hi) ^ (kr & 7)) * 8];
      accS = MFMA32(a, qf[dc], accS);
    }
    __builtin_amdgcn_s_setprio(0);

    // row max: max3-fused tree (T17) + one cross-half exchange
    float pm;
    {
      float t0 = fmax3(accS[0], accS[1], accS[2]);
      float t1 = fmax3(accS[3], accS[4], accS[5]);
      float t2 = fmax3(accS[6], accS[7], accS[8]);
      float t3 = fmax3(accS[9], accS[10], accS[11]);
      float t4 = fmax3(accS[12], accS[13], accS[14]);
      pm = fmax3(fmax3(t0, t1, t2), fmax3(t3, t4, accS[15]),
                 __builtin_inff() * -1.0f);
      pm = fmaxf(pm, __shfl_xor(pm, 32));
    }

    // defer-max (T13): rescale only when some row max grows by > 8 (log2)
    if (__ballot(pm > m_ + 8.0f)) {
      const float mn = fmaxf(m_, pm);
      const float sc = exp2f(m_ - mn);
      m_ = mn;
      l_ *= sc;
      if (hi == 0) sW[wave][l31] = sc;
#pragma unroll
      for (int r = 0; r < 16; ++r) {
        const float scr = sW[wave][(r & 3) + 8 * (r >> 2) + 4 * hi];
#pragma unroll
        for (int db = 0; db < 4; ++db) accO[db][r] *= scr;
      }
    }

    // p = 2^(s - m); per-half row sum via binary tree
    float sm[16];
#pragma unroll
    for (int j = 0; j < 16; ++j) {
      const float p = exp2f(accS[j] - m_);
      accS[j] = p;
      sm[j] = p;
    }
#pragma unroll
    for (int j = 0; j < 8; ++j) sm[j] += sm[j + 8];
#pragma unroll
    for (int j = 0; j < 4; ++j) sm[j] += sm[j + 4];
    l_ += (sm[0] + sm[1]) + (sm[2] + sm[3]);

    // pack P quads: pk[tq] covers k = 8*tq + 4*hi + {0..3}
    unsigned pk[4][2];
#pragma unroll
    for (int tq = 0; tq < 4; ++tq) {
      pk[tq][0] = pk2(accS[4 * tq + 0], accS[4 * tq + 1]);
      pk[tq][1] = pk2(accS[4 * tq + 2], accS[4 * tq + 3]);
    }

    // PV: 2 K=16 slices; A-frag via one lane-pair quad exchange per slice
    const __bf16* vt_ = sVt[cur];
#pragma unroll
    for (int kc = 0; kc < 2; ++kc) {
      const unsigned own0 = hi ? pk[2 * kc + 1][0] : pk[2 * kc][0];
      const unsigned own1 = hi ? pk[2 * kc + 1][1] : pk[2 * kc][1];
      const unsigned snd0 = hi ? pk[2 * kc][0] : pk[2 * kc + 1][0];
      const unsigned snd1 = hi ? pk[2 * kc][1] : pk[2 * kc + 1][1];
      const unsigned rc0 = (unsigned)__shfl_xor((int)snd0, 32);
      const unsigned rc1 = (unsigned)__shfl_xor((int)snd1, 32);
      u32x4 fr;
      fr[0] = hi ? rc0 : own0;
      fr[1] = hi ? rc1 : own1;
      fr[2] = hi ? own0 : rc0;
      fr[3] = hi ? own1 : rc1;
      const bf8_t pa = __builtin_bit_cast(bf8_t, fr);
      __builtin_amdgcn_s_setprio(1);
#pragma unroll
      for (int db = 0; db < 4; ++db) {
        const int dr = db * 32 + l31;
        const int p = (kc * 2 + hi) ^ ((dr >> 1) & 3);
        bf8_t vb = *(const bf8_t*)&vt_[dr * 32 + p * 8];
        accO[db] = MFMA32(pa, vb, accO[db]);
      }
      __builtin_amdgcn_s_setprio(0);
    }
  }

  // cross-half l reduce (once, not per tile)
  const float lf = l_ + __shfl_xor(l_, 32);

  // partial epilogue: unnormalized O (bf16) + (m,l) per q-row
  const size_t pbase = ((size_t)(z * 16 + bh) * 2048 + q0);
#pragma unroll
  for (int r = 0; r < 16; ++r) {
    const int qr = (r & 3) + 8 * (r >> 2) + 4 * hi;
    __bf16* op = Op + (pbase + qr) * 128 + l31;
#pragma unroll
    for (int db = 0; db < 4; ++db)
      op[db * 32] = (__bf16)(accO[db][r]);
  }
  if (hi == 0) {
    ml[(pbase + l31) * 2 + 0] = m_;
    ml[(pbase + l31) * 2 + 1] = lf;
  }
}

// ---------------------------------------------------------------------------
// Kernel 3b: merge the four KV-quarter partials (thread-coarsened x2).
// grid 512 blocks x 256 thr; block = (bh, 32-row chunk); thread = (row, 16-d).
// O = sum_i Oi*wi / sum_i li*wi, wi = 2^(mi - max_i mi).
// ---------------------------------------------------------------------------
__global__ __launch_bounds__(256) void attn_merge_k(
    const __bf16* __restrict__ Op, const float* __restrict__ ml,
    __bf16* __restrict__ Og) {
  const int bh = blockIdx.x >> 5, qc = blockIdx.x & 31;
  const int t = threadIdx.x;
  const int qr = qc * 64 + (t >> 3) * 2;    // 2 consecutive rows per... no:
  // 32-row chunk x 256 thr: row = qc*64? Recompute: 2048 rows / 32 chunks
  // = 64 rows per chunk; 256 thr = 64 rows x 4 d-quarters? Use:
  const int row = qc * 64 + (t >> 2);       // 64 rows
  const int d0 = (t & 3) * 32;              // 4 x 32-elem d-quarters
  const int b = bh >> 3, h = bh & 7;

  size_t idx[4];
  float mi[4], li[4];
  float m = -1e30f;
#pragma unroll
  for (int i = 0; i < 4; ++i) {
    idx[i] = ((size_t)(i * 16 + bh) * 2048 + row);
    mi[i] = ml[idx[i] * 2];
    li[i] = ml[idx[i] * 2 + 1];
    m = fmaxf(m, mi[i]);
  }
  float den = 0.f, w[4];
#pragma unroll
  for (int i = 0; i < 4; ++i) {
    w[i] = exp2f(mi[i] - m);
    den += li[i] * w[i];
  }
  const float inv = 1.0f / den;

#pragma unroll
  for (int g = 0; g < 4; ++g) {  // 4 x 8-elem groups = 32 d-elems
    float acc[8] = {0, 0, 0, 0, 0, 0, 0, 0};
#pragma unroll
    for (int i = 0; i < 4; ++i) {
      bf8_t o = *(const bf8_t*)(Op + idx[i] * 128 + d0 + g * 8);
#pragma unroll
      for (int j = 0; j < 8; ++j) acc[j] += (float)o[j] * w[i];
    }
    bf8_t r;
#pragma unroll
    for (int j = 0; j < 8; ++j) r[j] = (__bf16)(acc[j] * inv);
    *(bf8_t*)(Og + ((size_t)(b * 2048 + row) * 1024) + h * 128 + d0 + g * 8) = r;
  }
}

// ---------------------------------------------------------------------------
// Kernel 4: output projection + bias + LoRA-up. 64x128 tiles, 512 blocks.
// T1 XCD swizzle: xcd = lin&7 owns one Wo col-panel (L2-resident).
// ---------------------------------------------------------------------------
__global__ __launch_bounds__(256) void gemm_out_k(
    const __bf16* __restrict__ A, const __bf16* __restrict__ Wo,
    const float* __restrict__ bo, const float* __restrict__ lup,
    const float* __restrict__ tmp, float* __restrict__ out) {
  __shared__ __bf16 sA[64 * 64];
  __shared__ __bf16 sB[128 * 64];
  const int lin = blockIdx.x + 8 * blockIdx.y;
  const int bcol = lin & 7;
  const int brow = lin >> 3;
  const int K = 1024, N = 1024;
  f32x4 acc[2][4];
  gemm_tile<2>(A + (size_t)brow * 64 * K, Wo + (size_t)bcol * 128 * K, K, sA, sB, acc);

  const int lane = threadIdx.x & 63, wave = threadIdx.x >> 6;
  const int wr = (wave >> 1) * 32, wc = (wave & 1) * 64;
  for (int n = 0; n < 4; ++n) {
    const int col = bcol * 128 + wc + n * 16 + (lane & 15);
    const float bias = bo[col];
    const float u0 = lup[col * 4 + 0], u1 = lup[col * 4 + 1];
    const float u2 = lup[col * 4 + 2], u3 = lup[col * 4 + 3];
    for (int m = 0; m < 2; ++m)
      for (int j = 0; j < 4; ++j) {
        const int row = brow * 64 + wr + m * 16 + (lane >> 4) * 4 + j;
        const float* t = tmp + row * 4;
        float v = acc[m][n][j] + bias + t[0] * u0 + t[1] * u1 + t[2] * u2 + t[3] * u3;
        out[(size_t)row * N + col] = v;
      }
  }
}

// ---------------------------------------------------------------------------
extern "C" void kernel_launch(void* const* d_in, const int* in_sizes, int n_in,
                              void* d_out, int out_size, void* d_ws, size_t ws_size,
                              hipStream_t stream) {
  (void)in_sizes; (void)n_in; (void)out_size; (void)ws_size;
  const float* hs  = (const float*)d_in[0];
  const float* cs  = (const float*)d_in[1];
  const float* Wq  = (const float*)d_in[2];
  const float* Wk  = (const float*)d_in[3];
  const float* Wv  = (const float*)d_in[4];
  const float* Wo  = (const float*)d_in[5];
  const float* bo  = (const float*)d_in[6];
  const float* ldw = (const float*)d_in[7];
  const float* lup = (const float*)d_in[8];
  float* out = (float*)d_out;

  const size_t MD = (size_t)4096 * 1024;   // B*S*D
  const size_t WD = (size_t)1024 * 1024;   // D*D
  __bf16* hsb = (__bf16*)d_ws;
  __bf16* Wqb = hsb + MD;
  __bf16* Wkb = Wqb + WD;
  __bf16* Wvb = Wkb + WD;
  __bf16* Wob = Wvb + WD;
  __bf16* Qb  = Wob + WD;
  __bf16* Kb  = Qb + MD;
  __bf16* Vtb = Kb + MD;   // V^T: [h*128+d][b*2048+s] = [1024][4096]
  __bf16* Ab  = Vtb + MD;
  float*  tmp = (float*)(Ab + MD);              // [4096][4]
  __bf16* Opart = (__bf16*)(tmp + 4096 * 4);    // [4][16][2048][128] bf16
  float*  mlp   = (float*)(Opart + (size_t)4 * 16 * 2048 * 128);  // [4][16][2048][2]

  // 0) fp32->bf16 conversions + fused LoRA-down (y==5)
  cvt6_k<<<dim3(2048, 6), 256, 0, stream>>>(hs, Wq, Wk, Wv, Wo,
                                            hsb, Wqb, Wkb, Wvb, Wob,
                                            cs, ldw, tmp);
  gemm_qkv_k<<<dim3(8, 32, 3), 256, 0, stream>>>(hsb, Wqb, Wkb, Wvb, Qb, Kb, Vtb);
  flash_attn_k<<<dim3(16, 16, 4), 256, 0, stream>>>(Qb, Kb, Vtb, Opart, mlp);
  attn_merge_k<<<dim3(512), 256, 0, stream>>>(Opart, mlp, Ab);
  gemm_out_k<<<dim3(8, 64), 256, 0, stream>>>(Ab, Wob, bo, lup, tmp, out);
}

// Round 17
// 161.470 us; speedup vs baseline: 1.0261x; 1.0261x over previous
//
#include <hip/hip_runtime.h>
#include <hip/hip_bf16.h>

// B=2, S=2048, D=1024, H=8, HD=128, RANK=4.
// Device I/O buffers are FP32 (per reference dtypes).
// Internal pipeline: convert to bf16 in d_ws, bf16 MFMA with fp32 accum.
// V is produced TRANSPOSED by the QKV GEMM (operand swap). Flash attention
// (champion config): swapped QK^T 32x32x16, in-register softmax, KVBLK=32,
// dbuf K/V, 4-wave blocks (QBLK=128) sharing staged tiles, z=4, free
// register alloc (124 VGPR <= 128 cliff), XCD swizzle on flash + both GEMMs,
// max3-fused row-max. This is the measured-best R15 state (161.5 us);
// R16's lora-fusion + merge-coarsening regressed (+4.2 us) and is reverted.

typedef __bf16 bf8_t __attribute__((ext_vector_type(8)));
typedef float f32x4 __attribute__((ext_vector_type(4)));
typedef float f32x16 __attribute__((ext_vector_type(16)));
typedef unsigned u32x4 __attribute__((ext_vector_type(4)));

#define MFMA16(a, b, c) __builtin_amdgcn_mfma_f32_16x16x32_bf16((a), (b), (c), 0, 0, 0)
#define MFMA32(a, b, c) __builtin_amdgcn_mfma_f32_32x32x16_bf16((a), (b), (c), 0, 0, 0)

__device__ __forceinline__ void gload_lds16(const void* g, void* l) {
  __builtin_amdgcn_global_load_lds(
      (const __attribute__((address_space(1))) void*)g,
      (__attribute__((address_space(3))) void*)l, 16, 0, 0);
}

__device__ __forceinline__ unsigned pk2(float a, float b) {
  unsigned short ua = __builtin_bit_cast(unsigned short, (__bf16)a);
  unsigned short ub = __builtin_bit_cast(unsigned short, (__bf16)b);
  return (unsigned)ua | ((unsigned)ub << 16);
}

__device__ __forceinline__ float fmax3(float a, float b, float c) {
  return fmaxf(fmaxf(a, b), c);  // clang fuses to v_max3_f32
}

// ---------------------------------------------------------------------------
// Kernel 0: fp32 -> bf16 conversion (hidden_states + Wq,Wk,Wv,Wo).
// ---------------------------------------------------------------------------
__global__ __launch_bounds__(256) void cvt5_k(
    const float* __restrict__ s0, const float* __restrict__ s1,
    const float* __restrict__ s2, const float* __restrict__ s3,
    const float* __restrict__ s4, __bf16* __restrict__ d0,
    __bf16* __restrict__ d1, __bf16* __restrict__ d2, __bf16* __restrict__ d3,
    __bf16* __restrict__ d4) {
  const int which = blockIdx.y;
  const float* s = (which == 0) ? s0 : (which == 1) ? s1 : (which == 2) ? s2
                   : (which == 3) ? s3 : s4;
  __bf16* d = (which == 0) ? d0 : (which == 1) ? d1 : (which == 2) ? d2
              : (which == 3) ? d3 : d4;
  const int n = (which == 0) ? (4096 * 1024) : (1024 * 1024);
  const int i = (blockIdx.x * 256 + threadIdx.x) * 8;
  if (i >= n) return;
  float4 a = *(const float4*)(s + i);
  float4 b = *(const float4*)(s + i + 4);
  bf8_t r;
  r[0] = (__bf16)a.x; r[1] = (__bf16)a.y; r[2] = (__bf16)a.z; r[3] = (__bf16)a.w;
  r[4] = (__bf16)b.x; r[5] = (__bf16)b.y; r[6] = (__bf16)b.z; r[7] = (__bf16)b.w;
  *(bf8_t*)(d + i) = r;
}

// ---------------------------------------------------------------------------
// GEMM tile body, templated on per-wave M-fragments MR (tile = MR*32 x 128).
// ---------------------------------------------------------------------------
template <int MR>
__device__ __forceinline__ void gemm_tile(const __bf16* __restrict__ Abase,
                                          const __bf16* __restrict__ Wbase,
                                          int K, __bf16* sA, __bf16* sB,
                                          f32x4 acc[MR][4]) {
  const int tid = threadIdx.x;
  const int wave = tid >> 6, lane = tid & 63;
  const int wr = (wave >> 1) * (MR * 16), wc = (wave & 1) * 64;
  const int lrow = lane >> 3, lchunk = lane & 7;

  for (int m = 0; m < MR; ++m)
    for (int n = 0; n < 4; ++n)
      acc[m][n] = f32x4{0.f, 0.f, 0.f, 0.f};

  for (int k0 = 0; k0 < K; k0 += 64) {
    for (int i = 0; i < MR; ++i) {
      const int rbase = i * 32 + wave * 8;
      gload_lds16(Abase + (size_t)(rbase + lrow) * K + k0 + lchunk * 8,
                  sA + rbase * 64);
    }
    for (int i = 0; i < 4; ++i) {
      const int rbase = i * 32 + wave * 8;
      gload_lds16(Wbase + (size_t)(rbase + lrow) * K + k0 + lchunk * 8,
                  sB + rbase * 64);
    }
    __syncthreads();

    for (int kk = 0; kk < 2; ++kk) {
      bf8_t af[MR], bfr[4];
      const int koff = kk * 32 + (lane >> 4) * 8;
      for (int m = 0; m < MR; ++m)
        af[m] = *(const bf8_t*)&sA[(wr + m * 16 + (lane & 15)) * 64 + koff];
      for (int n = 0; n < 4; ++n)
        bfr[n] = *(const bf8_t*)&sB[(wc + n * 16 + (lane & 15)) * 64 + koff];
      for (int m = 0; m < MR; ++m)
        for (int n = 0; n < 4; ++n)
          acc[m][n] = MFMA16(af[m], bfr[n], acc[m][n]);
    }
    __syncthreads();
  }
}

// ---------------------------------------------------------------------------
// Kernel 1: QKV projections. z==0/1: C = X.W^T; z==2: operands swapped so the
// output IS V^T: Vt[h*128+d][b*2048+s] (row-major [1024][4096]).
// T1 XCD swizzle: panel index = lin&7 = XCD owner (weights L2-resident).
// ---------------------------------------------------------------------------
__global__ __launch_bounds__(256) void gemm_qkv_k(
    const __bf16* __restrict__ X, const __bf16* __restrict__ Wq,
    const __bf16* __restrict__ Wk, const __bf16* __restrict__ Wv,
    __bf16* __restrict__ Qb, __bf16* __restrict__ Kb, __bf16* __restrict__ Vtb) {
  __shared__ __bf16 sA[128 * 64];
  __shared__ __bf16 sB[128 * 64];
  const int lin = blockIdx.x + 8 * (blockIdx.y + 32 * blockIdx.z);
  const int p8 = lin & 7;            // weight-panel index (8) = XCD owner
  const int rest = lin >> 3;
  const int p32 = rest & 31;         // row/s-tile index (32)
  const int z = rest >> 5;           // 0..2
  const int K = 1024;
  int rowT, colT, Nout;
  const __bf16 *Abase, *Wbase;
  __bf16* C;
  if (z == 2) {
    rowT = p8; colT = p32; Nout = 4096;
    Abase = Wv + (size_t)rowT * 128 * K;
    Wbase = X + (size_t)colT * 128 * K;
    C = Vtb;
  } else {
    rowT = p32; colT = p8; Nout = 1024;
    Abase = X + (size_t)rowT * 128 * K;
    Wbase = ((z == 0) ? Wq : Wk) + (size_t)colT * 128 * K;
    C = (z == 0) ? Qb : Kb;
  }
  f32x4 acc[4][4];
  gemm_tile<4>(Abase, Wbase, K, sA, sB, acc);

  const int lane = threadIdx.x & 63, wave = threadIdx.x >> 6;
  const int wr = (wave >> 1) * 64, wc = (wave & 1) * 64;
  const int row0 = rowT * 128 + wr + (lane >> 4) * 4;
  const int col0 = colT * 128 + wc + (lane & 15);
  for (int m = 0; m < 4; ++m)
    for (int n = 0; n < 4; ++n)
      for (int j = 0; j < 4; ++j)
        C[(size_t)(row0 + m * 16 + j) * Nout + col0 + n * 16] = (__bf16)acc[m][n][j];
}

// ---------------------------------------------------------------------------
// Kernel 2: LoRA down: tmp[s][r] = sum_d control[s][d]*down[r][d]. FP32 in.
// ---------------------------------------------------------------------------
__global__ __launch_bounds__(256) void lora_down_k(
    const float* __restrict__ ctrl, const float* __restrict__ down,
    float* __restrict__ tmp) {
  const int tid = threadIdx.x, wave = tid >> 6, lane = tid & 63;
  const int s = blockIdx.x * 4 + wave;
  const float* cp = ctrl + (size_t)s * 1024 + lane * 16;
  float4 c[4];
  for (int i = 0; i < 4; ++i) c[i] = *(const float4*)(cp + i * 4);
  for (int r = 0; r < 4; ++r) {
    const float* dp = down + r * 1024 + lane * 16;
    float acc = 0.f;
    for (int i = 0; i < 4; ++i) {
      float4 dv = *(const float4*)(dp + i * 4);
      acc += c[i].x * dv.x + c[i].y * dv.y + c[i].z * dv.z + c[i].w * dv.w;
    }
    for (int off = 32; off > 0; off >>= 1) acc += __shfl_xor(acc, off);
    if (lane == 0) tmp[s * 4 + r] = acc;
  }
}

// ---------------------------------------------------------------------------
// Kernel 3: flash attention partial pass. 4-wave blocks (QBLK=128) sharing
// DOUBLE-buffered K/V tiles; KVBLK=32; z=4 kv-quarters; NO register cap
// (124 VGPR <= 128 cliff). grid 1024 blocks x 256 thr = 4 blocks/CU.
// XCD swizzle: xcd = lin&7 owns bh pair.
// ---------------------------------------------------------------------------
__global__ __launch_bounds__(256) void flash_attn_k(
    const __bf16* __restrict__ Qg, const __bf16* __restrict__ Kg,
    const __bf16* __restrict__ Vtg, __bf16* __restrict__ Op,
    float* __restrict__ ml) {
  const int S = 2048, D = 1024;
  const int NT = 16;  // KVBLK=32 tiles per kv-quarter
  __shared__ __bf16 sK[2][32 * 128];
  __shared__ __bf16 sVt[2][128 * 32];
  __shared__ float sW[4][32];

  // XCD-aware bijective remap (grid (16,16,4) -> 1024 linear ids)
  const int lin = blockIdx.x + 16 * (blockIdx.y + 16 * blockIdx.z);
  const int bh = (lin & 7) * 2 + ((lin >> 9) & 1);
  const int qt = (lin >> 3) & 15;
  const int z = (lin >> 7) & 3;

  const int b = bh >> 3, h = bh & 7;
  const int tid = threadIdx.x, wave = tid >> 6, lane = tid & 63;
  const int l31 = lane & 31, hi = lane >> 5;
  const size_t base = (size_t)b * S * D + (size_t)h * 128;
  const size_t vtbase = (size_t)h * 128 * 4096 + (size_t)b * 2048;
  const int q0 = qt * 128 + wave * 32;
  const int kvofs = z * 512;

  // Q as B-fragments, pre-scaled by (1/sqrt(128))*log2(e) (exp2 domain).
  bf8_t qf[8];
  {
    const float c = 0.08838834764831845f * 1.4426950408889634f;
    const __bf16* qp = Qg + base + (size_t)(q0 + l31) * D + hi * 8;
#pragma unroll
    for (int dc = 0; dc < 8; ++dc) {
      bf8_t v = *(const bf8_t*)(qp + dc * 16);
#pragma unroll
      for (int j = 0; j < 8; ++j) v[j] = (__bf16)((float)v[j] * c);
      qf[dc] = v;
    }
  }

  f32x16 accO[4];
#pragma unroll
  for (int db = 0; db < 4; ++db)
#pragma unroll
    for (int j = 0; j < 16; ++j) accO[db][j] = 0.f;
  float m_ = -1e30f, l_ = 0.f;  // l_ is PER-HALF; cross-half reduce at end

  // staging: K tile 8 KB = 8 issues (2/wave); V tile 8 KB = 8 issues (2/wave)
  auto stageK = [&](int buf, int kv) {
#pragma unroll
    for (int i = 0; i < 2; ++i) {
      const int r = wave * 8 + i * 4 + (lane >> 4);
      const int gc = (lane & 15) ^ (r & 7);
      gload_lds16(Kg + base + (size_t)(kvofs + kv + r) * D + gc * 8,
                  &sK[buf][(wave * 8 + i * 4) * 128]);
    }
  };
  auto stageV = [&](int buf, int kv) {
#pragma unroll
    for (int i = 0; i < 2; ++i) {
      const int d = wave * 32 + i * 16 + (lane >> 2);
      const int gc = (lane & 3) ^ ((d >> 1) & 3);
      gload_lds16(Vtg + vtbase + (size_t)d * 4096 + kvofs + kv + gc * 8,
                  &sVt[buf][(wave * 32 + i * 16) * 32]);
    }
  };

  stageK(0, 0);
  stageV(0, 0);

  for (int t = 0; t < NT; ++t) {
    const int cur = t & 1;
    __syncthreads();  // drains DMA for buf[cur]; guards buf[cur^1] reuse
    if (t < NT - 1) {
      stageK(cur ^ 1, (t + 1) * 32);
      stageV(cur ^ 1, (t + 1) * 32);
    }

    // QK^T swapped: accS holds S[k][q]; q = l31 (lane-local row),
    // k = (r&3) + 8*(r>>2) + 4*hi. Single chain (VGPR <= 128, R11 cliff).
    f32x16 accS;
#pragma unroll
    for (int j = 0; j < 16; ++j) accS[j] = 0.f;
    const __bf16* kb_ = sK[cur];
    const int kr = l31;
    __builtin_amdgcn_s_setprio(1);
#pragma unroll
    for (int dc = 0; dc < 8; ++dc) {
      bf8_t a = *(const bf8_t*)&kb_[kr * 128 + ((2 * dc + hi) ^ (kr & 7)) * 8];
      accS = MFMA32(a, qf[dc], accS);
    }
    __builtin_amdgcn_s_setprio(0);

    // row max: max3-fused tree (T17) + one cross-half exchange
    float pm;
    {
      float t0 = fmax3(accS[0], accS[1], accS[2]);
      float t1 = fmax3(accS[3], accS[4], accS[5]);
      float t2 = fmax3(accS[6], accS[7], accS[8]);
      float t3 = fmax3(accS[9], accS[10], accS[11]);
      float t4 = fmax3(accS[12], accS[13], accS[14]);
      pm = fmax3(fmax3(t0, t1, t2), fmax3(t3, t4, accS[15]),
                 __builtin_inff() * -1.0f);
      pm = fmaxf(pm, __shfl_xor(pm, 32));
    }

    // defer-max (T13): rescale only when some row max grows by > 8 (log2)
    if (__ballot(pm > m_ + 8.0f)) {
      const float mn = fmaxf(m_, pm);
      const float sc = exp2f(m_ - mn);
      m_ = mn;
      l_ *= sc;
      if (hi == 0) sW[wave][l31] = sc;
#pragma unroll
      for (int r = 0; r < 16; ++r) {
        const float scr = sW[wave][(r & 3) + 8 * (r >> 2) + 4 * hi];
#pragma unroll
        for (int db = 0; db < 4; ++db) accO[db][r] *= scr;
      }
    }

    // p = 2^(s - m); per-half row sum via binary tree (no per-tile shuffle)
    float sm[16];
#pragma unroll
    for (int j = 0; j < 16; ++j) {
      const float p = exp2f(accS[j] - m_);
      accS[j] = p;
      sm[j] = p;
    }
#pragma unroll
    for (int j = 0; j < 8; ++j) sm[j] += sm[j + 8];
#pragma unroll
    for (int j = 0; j < 4; ++j) sm[j] += sm[j + 4];
    l_ += (sm[0] + sm[1]) + (sm[2] + sm[3]);

    // pack P quads: pk[tq] covers k = 8*tq + 4*hi + {0..3}
    unsigned pk[4][2];
#pragma unroll
    for (int tq = 0; tq < 4; ++tq) {
      pk[tq][0] = pk2(accS[4 * tq + 0], accS[4 * tq + 1]);
      pk[tq][1] = pk2(accS[4 * tq + 2], accS[4 * tq + 3]);
    }

    // PV: 2 K=16 slices; A-frag via one lane-pair quad exchange per slice
    const __bf16* vt_ = sVt[cur];
#pragma unroll
    for (int kc = 0; kc < 2; ++kc) {
      const unsigned own0 = hi ? pk[2 * kc + 1][0] : pk[2 * kc][0];
      const unsigned own1 = hi ? pk[2 * kc + 1][1] : pk[2 * kc][1];
      const unsigned snd0 = hi ? pk[2 * kc][0] : pk[2 * kc + 1][0];
      const unsigned snd1 = hi ? pk[2 * kc][1] : pk[2 * kc + 1][1];
      const unsigned rc0 = (unsigned)__shfl_xor((int)snd0, 32);
      const unsigned rc1 = (unsigned)__shfl_xor((int)snd1, 32);
      u32x4 fr;
      fr[0] = hi ? rc0 : own0;
      fr[1] = hi ? rc1 : own1;
      fr[2] = hi ? own0 : rc0;
      fr[3] = hi ? own1 : rc1;
      const bf8_t pa = __builtin_bit_cast(bf8_t, fr);
      __builtin_amdgcn_s_setprio(1);
#pragma unroll
      for (int db = 0; db < 4; ++db) {
        const int dr = db * 32 + l31;
        const int p = (kc * 2 + hi) ^ ((dr >> 1) & 3);
        bf8_t vb = *(const bf8_t*)&vt_[dr * 32 + p * 8];
        accO[db] = MFMA32(pa, vb, accO[db]);
      }
      __builtin_amdgcn_s_setprio(0);
    }
  }

  // cross-half l reduce (once, not per tile)
  const float lf = l_ + __shfl_xor(l_, 32);

  // partial epilogue: unnormalized O (bf16) + (m,l) per q-row
  const size_t pbase = ((size_t)(z * 16 + bh) * 2048 + q0);
#pragma unroll
  for (int r = 0; r < 16; ++r) {
    const int qr = (r & 3) + 8 * (r >> 2) + 4 * hi;
    __bf16* op = Op + (pbase + qr) * 128 + l31;
#pragma unroll
    for (int db = 0; db < 4; ++db)
      op[db * 32] = (__bf16)(accO[db][r]);
  }
  if (hi == 0) {
    ml[(pbase + l31) * 2 + 0] = m_;
    ml[(pbase + l31) * 2 + 1] = lf;
  }
}

// ---------------------------------------------------------------------------
// Kernel 3b: merge the four KV-quarter partials.
// O = sum_i Oi*wi / sum_i li*wi, wi = 2^(mi - max_i mi).
// ---------------------------------------------------------------------------
__global__ __launch_bounds__(256) void attn_merge_k(
    const __bf16* __restrict__ Op, const float* __restrict__ ml,
    __bf16* __restrict__ Og) {
  const int bh = blockIdx.x >> 7, qc = blockIdx.x & 127;
  const int t = threadIdx.x;
  const int qr = qc * 16 + (t >> 4);
  const int d0 = (t & 15) * 8;
  const int b = bh >> 3, h = bh & 7;

  size_t idx[4];
  float mi[4], li[4];
  float m = -1e30f;
#pragma unroll
  for (int i = 0; i < 4; ++i) {
    idx[i] = ((size_t)(i * 16 + bh) * 2048 + qr);
    mi[i] = ml[idx[i] * 2];
    li[i] = ml[idx[i] * 2 + 1];
    m = fmaxf(m, mi[i]);
  }
  float den = 0.f, w[4];
#pragma unroll
  for (int i = 0; i < 4; ++i) {
    w[i] = exp2f(mi[i] - m);
    den += li[i] * w[i];
  }
  const float inv = 1.0f / den;

  float acc[8] = {0, 0, 0, 0, 0, 0, 0, 0};
#pragma unroll
  for (int i = 0; i < 4; ++i) {
    bf8_t o = *(const bf8_t*)(Op + idx[i] * 128 + d0);
#pragma unroll
    for (int j = 0; j < 8; ++j) acc[j] += (float)o[j] * w[i];
  }
  bf8_t r;
#pragma unroll
  for (int j = 0; j < 8; ++j) r[j] = (__bf16)(acc[j] * inv);
  *(bf8_t*)(Og + ((size_t)(b * 2048 + qr) * 1024) + h * 128 + d0) = r;
}

// ---------------------------------------------------------------------------
// Kernel 4: output projection + bias + LoRA-up. 64x128 tiles, 512 blocks.
// T1 XCD swizzle: xcd = lin&7 owns one Wo col-panel (L2-resident).
// ---------------------------------------------------------------------------
__global__ __launch_bounds__(256) void gemm_out_k(
    const __bf16* __restrict__ A, const __bf16* __restrict__ Wo,
    const float* __restrict__ bo, const float* __restrict__ lup,
    const float* __restrict__ tmp, float* __restrict__ out) {
  __shared__ __bf16 sA[64 * 64];
  __shared__ __bf16 sB[128 * 64];
  const int lin = blockIdx.x + 8 * blockIdx.y;
  const int bcol = lin & 7;     // Wo panel = XCD owner
  const int brow = lin >> 3;    // 0..63
  const int K = 1024, N = 1024;
  f32x4 acc[2][4];
  gemm_tile<2>(A + (size_t)brow * 64 * K, Wo + (size_t)bcol * 128 * K, K, sA, sB, acc);

  const int lane = threadIdx.x & 63, wave = threadIdx.x >> 6;
  const int wr = (wave >> 1) * 32, wc = (wave & 1) * 64;
  for (int n = 0; n < 4; ++n) {
    const int col = bcol * 128 + wc + n * 16 + (lane & 15);
    const float bias = bo[col];
    const float u0 = lup[col * 4 + 0], u1 = lup[col * 4 + 1];
    const float u2 = lup[col * 4 + 2], u3 = lup[col * 4 + 3];
    for (int m = 0; m < 2; ++m)
      for (int j = 0; j < 4; ++j) {
        const int row = brow * 64 + wr + m * 16 + (lane >> 4) * 4 + j;
        const float* t = tmp + row * 4;
        float v = acc[m][n][j] + bias + t[0] * u0 + t[1] * u1 + t[2] * u2 + t[3] * u3;
        out[(size_t)row * N + col] = v;
      }
  }
}

// ---------------------------------------------------------------------------
extern "C" void kernel_launch(void* const* d_in, const int* in_sizes, int n_in,
                              void* d_out, int out_size, void* d_ws, size_t ws_size,
                              hipStream_t stream) {
  (void)in_sizes; (void)n_in; (void)out_size; (void)ws_size;
  const float* hs  = (const float*)d_in[0];
  const float* cs  = (const float*)d_in[1];
  const float* Wq  = (const float*)d_in[2];
  const float* Wk  = (const float*)d_in[3];
  const float* Wv  = (const float*)d_in[4];
  const float* Wo  = (const float*)d_in[5];
  const float* bo  = (const float*)d_in[6];
  const float* ldw = (const float*)d_in[7];
  const float* lup = (const float*)d_in[8];
  float* out = (float*)d_out;

  const size_t MD = (size_t)4096 * 1024;   // B*S*D
  const size_t WD = (size_t)1024 * 1024;   // D*D
  __bf16* hsb = (__bf16*)d_ws;
  __bf16* Wqb = hsb + MD;
  __bf16* Wkb = Wqb + WD;
  __bf16* Wvb = Wkb + WD;
  __bf16* Wob = Wvb + WD;
  __bf16* Qb  = Wob + WD;
  __bf16* Kb  = Qb + MD;
  __bf16* Vtb = Kb + MD;   // V^T: [h*128+d][b*2048+s] = [1024][4096]
  __bf16* Ab  = Vtb + MD;
  float*  tmp = (float*)(Ab + MD);              // [4096][4]
  __bf16* Opart = (__bf16*)(tmp + 4096 * 4);    // [4][16][2048][128] bf16
  float*  mlp   = (float*)(Opart + (size_t)4 * 16 * 2048 * 128);  // [4][16][2048][2]

  cvt5_k<<<dim3(2048, 5), 256, 0, stream>>>(hs, Wq, Wk, Wv, Wo,
                                            hsb, Wqb, Wkb, Wvb, Wob);
  gemm_qkv_k<<<dim3(8, 32, 3), 256, 0, stream>>>(hsb, Wqb, Wkb, Wvb, Qb, Kb, Vtb);
  lora_down_k<<<dim3(1024), 256, 0, stream>>>(cs, ldw, tmp);
  flash_attn_k<<<dim3(16, 16, 4), 256, 0, stream>>>(Qb, Kb, Vtb, Opart, mlp);
  attn_merge_k<<<dim3(2048), 256, 0, stream>>>(Opart, mlp, Ab);
  gemm_out_k<<<dim3(8, 64), 256, 0, stream>>>(Ab, Wob, bo, lup, tmp, out);
}

// Round 18
// 158.464 us; speedup vs baseline: 1.0456x; 1.0190x over previous
//
#include <hip/hip_runtime.h>
#include <hip/hip_bf16.h>

// B=2, S=2048, D=1024, H=8, HD=128, RANK=4.
// Device I/O buffers are FP32 (per reference dtypes).
// Internal pipeline: convert to bf16 in d_ws, bf16 MFMA with fp32 accum.
// V is produced TRANSPOSED by the QKV GEMM (operand swap). Flash attention
// (champion config): swapped QK^T 32x32x16, in-register softmax, KVBLK=32,
// dbuf K/V, 4-wave blocks (QBLK=128) sharing staged tiles, z=4, free
// register alloc (124 VGPR <= 128 cliff), XCD swizzle on flash + both GEMMs.
// R18 consolidation: setprio removed from flash (4-wave lockstep blocks =
// m190 null/negative regime), cvt grid right-sized (no empty blocks),
// gemm_out epilogue loads vectorized+hoisted.

typedef __bf16 bf8_t __attribute__((ext_vector_type(8)));
typedef float f32x4 __attribute__((ext_vector_type(4)));
typedef float f32x16 __attribute__((ext_vector_type(16)));
typedef unsigned u32x4 __attribute__((ext_vector_type(4)));

#define MFMA16(a, b, c) __builtin_amdgcn_mfma_f32_16x16x32_bf16((a), (b), (c), 0, 0, 0)
#define MFMA32(a, b, c) __builtin_amdgcn_mfma_f32_32x32x16_bf16((a), (b), (c), 0, 0, 0)

__device__ __forceinline__ void gload_lds16(const void* g, void* l) {
  __builtin_amdgcn_global_load_lds(
      (const __attribute__((address_space(1))) void*)g,
      (__attribute__((address_space(3))) void*)l, 16, 0, 0);
}

__device__ __forceinline__ unsigned pk2(float a, float b) {
  unsigned short ua = __builtin_bit_cast(unsigned short, (__bf16)a);
  unsigned short ub = __builtin_bit_cast(unsigned short, (__bf16)b);
  return (unsigned)ua | ((unsigned)ub << 16);
}

__device__ __forceinline__ float fmax3(float a, float b, float c) {
  return fmaxf(fmaxf(a, b), c);  // clang fuses to v_max3_f32
}

// ---------------------------------------------------------------------------
// Kernel 0: fp32 -> bf16 conversion. 1D grid, exact sizing:
// blocks [0,2048) = hidden_states (4M elems); then 4 x 512 blocks for
// Wq,Wk,Wv,Wo (1M each). 8 elems/thread, no bounds checks (exact fit).
// ---------------------------------------------------------------------------
__global__ __launch_bounds__(256) void cvt5_k(
    const float* __restrict__ s0, const float* __restrict__ s1,
    const float* __restrict__ s2, const float* __restrict__ s3,
    const float* __restrict__ s4, __bf16* __restrict__ d0,
    __bf16* __restrict__ d1, __bf16* __restrict__ d2, __bf16* __restrict__ d3,
    __bf16* __restrict__ d4) {
  const int blk = blockIdx.x;
  int which, off;
  if (blk < 2048) {
    which = 0; off = blk;
  } else {
    const int w = blk - 2048;
    which = 1 + (w >> 9);
    off = w & 511;
  }
  const float* s = (which == 0) ? s0 : (which == 1) ? s1 : (which == 2) ? s2
                   : (which == 3) ? s3 : s4;
  __bf16* d = (which == 0) ? d0 : (which == 1) ? d1 : (which == 2) ? d2
              : (which == 3) ? d3 : d4;
  const int i = (off * 256 + threadIdx.x) * 8;
  float4 a = *(const float4*)(s + i);
  float4 b = *(const float4*)(s + i + 4);
  bf8_t r;
  r[0] = (__bf16)a.x; r[1] = (__bf16)a.y; r[2] = (__bf16)a.z; r[3] = (__bf16)a.w;
  r[4] = (__bf16)b.x; r[5] = (__bf16)b.y; r[6] = (__bf16)b.z; r[7] = (__bf16)b.w;
  *(bf8_t*)(d + i) = r;
}

// ---------------------------------------------------------------------------
// GEMM tile body, templated on per-wave M-fragments MR (tile = MR*32 x 128).
// ---------------------------------------------------------------------------
template <int MR>
__device__ __forceinline__ void gemm_tile(const __bf16* __restrict__ Abase,
                                          const __bf16* __restrict__ Wbase,
                                          int K, __bf16* sA, __bf16* sB,
                                          f32x4 acc[MR][4]) {
  const int tid = threadIdx.x;
  const int wave = tid >> 6, lane = tid & 63;
  const int wr = (wave >> 1) * (MR * 16), wc = (wave & 1) * 64;
  const int lrow = lane >> 3, lchunk = lane & 7;

  for (int m = 0; m < MR; ++m)
    for (int n = 0; n < 4; ++n)
      acc[m][n] = f32x4{0.f, 0.f, 0.f, 0.f};

  for (int k0 = 0; k0 < K; k0 += 64) {
    for (int i = 0; i < MR; ++i) {
      const int rbase = i * 32 + wave * 8;
      gload_lds16(Abase + (size_t)(rbase + lrow) * K + k0 + lchunk * 8,
                  sA + rbase * 64);
    }
    for (int i = 0; i < 4; ++i) {
      const int rbase = i * 32 + wave * 8;
      gload_lds16(Wbase + (size_t)(rbase + lrow) * K + k0 + lchunk * 8,
                  sB + rbase * 64);
    }
    __syncthreads();

    for (int kk = 0; kk < 2; ++kk) {
      bf8_t af[MR], bfr[4];
      const int koff = kk * 32 + (lane >> 4) * 8;
      for (int m = 0; m < MR; ++m)
        af[m] = *(const bf8_t*)&sA[(wr + m * 16 + (lane & 15)) * 64 + koff];
      for (int n = 0; n < 4; ++n)
        bfr[n] = *(const bf8_t*)&sB[(wc + n * 16 + (lane & 15)) * 64 + koff];
      for (int m = 0; m < MR; ++m)
        for (int n = 0; n < 4; ++n)
          acc[m][n] = MFMA16(af[m], bfr[n], acc[m][n]);
    }
    __syncthreads();
  }
}

// ---------------------------------------------------------------------------
// Kernel 1: QKV projections. z==0/1: C = X.W^T; z==2: operands swapped so the
// output IS V^T: Vt[h*128+d][b*2048+s] (row-major [1024][4096]).
// T1 XCD swizzle: panel index = lin&7 = XCD owner (weights L2-resident).
// ---------------------------------------------------------------------------
__global__ __launch_bounds__(256) void gemm_qkv_k(
    const __bf16* __restrict__ X, const __bf16* __restrict__ Wq,
    const __bf16* __restrict__ Wk, const __bf16* __restrict__ Wv,
    __bf16* __restrict__ Qb, __bf16* __restrict__ Kb, __bf16* __restrict__ Vtb) {
  __shared__ __bf16 sA[128 * 64];
  __shared__ __bf16 sB[128 * 64];
  const int lin = blockIdx.x + 8 * (blockIdx.y + 32 * blockIdx.z);
  const int p8 = lin & 7;            // weight-panel index (8) = XCD owner
  const int rest = lin >> 3;
  const int p32 = rest & 31;         // row/s-tile index (32)
  const int z = rest >> 5;           // 0..2
  const int K = 1024;
  int rowT, colT, Nout;
  const __bf16 *Abase, *Wbase;
  __bf16* C;
  if (z == 2) {
    rowT = p8; colT = p32; Nout = 4096;
    Abase = Wv + (size_t)rowT * 128 * K;
    Wbase = X + (size_t)colT * 128 * K;
    C = Vtb;
  } else {
    rowT = p32; colT = p8; Nout = 1024;
    Abase = X + (size_t)rowT * 128 * K;
    Wbase = ((z == 0) ? Wq : Wk) + (size_t)colT * 128 * K;
    C = (z == 0) ? Qb : Kb;
  }
  f32x4 acc[4][4];
  gemm_tile<4>(Abase, Wbase, K, sA, sB, acc);

  const int lane = threadIdx.x & 63, wave = threadIdx.x >> 6;
  const int wr = (wave >> 1) * 64, wc = (wave & 1) * 64;
  const int row0 = rowT * 128 + wr + (lane >> 4) * 4;
  const int col0 = colT * 128 + wc + (lane & 15);
  for (int m = 0; m < 4; ++m)
    for (int n = 0; n < 4; ++n)
      for (int j = 0; j < 4; ++j)
        C[(size_t)(row0 + m * 16 + j) * Nout + col0 + n * 16] = (__bf16)acc[m][n][j];
}

// ---------------------------------------------------------------------------
// Kernel 2: LoRA down: tmp[s][r] = sum_d control[s][d]*down[r][d]. FP32 in.
// ---------------------------------------------------------------------------
__global__ __launch_bounds__(256) void lora_down_k(
    const float* __restrict__ ctrl, const float* __restrict__ down,
    float* __restrict__ tmp) {
  const int tid = threadIdx.x, wave = tid >> 6, lane = tid & 63;
  const int s = blockIdx.x * 4 + wave;
  const float* cp = ctrl + (size_t)s * 1024 + lane * 16;
  float4 c[4];
  for (int i = 0; i < 4; ++i) c[i] = *(const float4*)(cp + i * 4);
  for (int r = 0; r < 4; ++r) {
    const float* dp = down + r * 1024 + lane * 16;
    float acc = 0.f;
    for (int i = 0; i < 4; ++i) {
      float4 dv = *(const float4*)(dp + i * 4);
      acc += c[i].x * dv.x + c[i].y * dv.y + c[i].z * dv.z + c[i].w * dv.w;
    }
    for (int off = 32; off > 0; off >>= 1) acc += __shfl_xor(acc, off);
    if (lane == 0) tmp[s * 4 + r] = acc;
  }
}

// ---------------------------------------------------------------------------
// Kernel 3: flash attention partial pass. 4-wave blocks (QBLK=128) sharing
// DOUBLE-buffered K/V tiles; KVBLK=32; z=4 kv-quarters; NO register cap
// (124 VGPR <= 128 cliff). grid 1024 blocks x 256 thr = 4 blocks/CU.
// XCD swizzle: xcd = lin&7 owns bh pair. setprio REMOVED (lockstep waves).
// ---------------------------------------------------------------------------
__global__ __launch_bounds__(256) void flash_attn_k(
    const __bf16* __restrict__ Qg, const __bf16* __restrict__ Kg,
    const __bf16* __restrict__ Vtg, __bf16* __restrict__ Op,
    float* __restrict__ ml) {
  const int S = 2048, D = 1024;
  const int NT = 16;  // KVBLK=32 tiles per kv-quarter
  __shared__ __bf16 sK[2][32 * 128];
  __shared__ __bf16 sVt[2][128 * 32];
  __shared__ float sW[4][32];

  // XCD-aware bijective remap (grid (16,16,4) -> 1024 linear ids)
  const int lin = blockIdx.x + 16 * (blockIdx.y + 16 * blockIdx.z);
  const int bh = (lin & 7) * 2 + ((lin >> 9) & 1);
  const int qt = (lin >> 3) & 15;
  const int z = (lin >> 7) & 3;

  const int b = bh >> 3, h = bh & 7;
  const int tid = threadIdx.x, wave = tid >> 6, lane = tid & 63;
  const int l31 = lane & 31, hi = lane >> 5;
  const size_t base = (size_t)b * S * D + (size_t)h * 128;
  const size_t vtbase = (size_t)h * 128 * 4096 + (size_t)b * 2048;
  const int q0 = qt * 128 + wave * 32;
  const int kvofs = z * 512;

  // Q as B-fragments, pre-scaled by (1/sqrt(128))*log2(e) (exp2 domain).
  bf8_t qf[8];
  {
    const float c = 0.08838834764831845f * 1.4426950408889634f;
    const __bf16* qp = Qg + base + (size_t)(q0 + l31) * D + hi * 8;
#pragma unroll
    for (int dc = 0; dc < 8; ++dc) {
      bf8_t v = *(const bf8_t*)(qp + dc * 16);
#pragma unroll
      for (int j = 0; j < 8; ++j) v[j] = (__bf16)((float)v[j] * c);
      qf[dc] = v;
    }
  }

  f32x16 accO[4];
#pragma unroll
  for (int db = 0; db < 4; ++db)
#pragma unroll
    for (int j = 0; j < 16; ++j) accO[db][j] = 0.f;
  float m_ = -1e30f, l_ = 0.f;  // l_ is PER-HALF; cross-half reduce at end

  // staging: K tile 8 KB = 8 issues (2/wave); V tile 8 KB = 8 issues (2/wave)
  auto stageK = [&](int buf, int kv) {
#pragma unroll
    for (int i = 0; i < 2; ++i) {
      const int r = wave * 8 + i * 4 + (lane >> 4);
      const int gc = (lane & 15) ^ (r & 7);
      gload_lds16(Kg + base + (size_t)(kvofs + kv + r) * D + gc * 8,
                  &sK[buf][(wave * 8 + i * 4) * 128]);
    }
  };
  auto stageV = [&](int buf, int kv) {
#pragma unroll
    for (int i = 0; i < 2; ++i) {
      const int d = wave * 32 + i * 16 + (lane >> 2);
      const int gc = (lane & 3) ^ ((d >> 1) & 3);
      gload_lds16(Vtg + vtbase + (size_t)d * 4096 + kvofs + kv + gc * 8,
                  &sVt[buf][(wave * 32 + i * 16) * 32]);
    }
  };

  stageK(0, 0);
  stageV(0, 0);

  for (int t = 0; t < NT; ++t) {
    const int cur = t & 1;
    __syncthreads();  // drains DMA for buf[cur]; guards buf[cur^1] reuse
    if (t < NT - 1) {
      stageK(cur ^ 1, (t + 1) * 32);
      stageV(cur ^ 1, (t + 1) * 32);
    }

    // QK^T swapped: accS holds S[k][q]; q = l31 (lane-local row),
    // k = (r&3) + 8*(r>>2) + 4*hi. Single chain (VGPR <= 128, R11 cliff).
    f32x16 accS;
#pragma unroll
    for (int j = 0; j < 16; ++j) accS[j] = 0.f;
    const __bf16* kb_ = sK[cur];
    const int kr = l31;
#pragma unroll
    for (int dc = 0; dc < 8; ++dc) {
      bf8_t a = *(const bf8_t*)&kb_[kr * 128 + ((2 * dc + hi) ^ (kr & 7)) * 8];
      accS = MFMA32(a, qf[dc], accS);
    }

    // row max: max3-fused tree (T17) + one cross-half exchange
    float pm;
    {
      float t0 = fmax3(accS[0], accS[1], accS[2]);
      float t1 = fmax3(accS[3], accS[4], accS[5]);
      float t2 = fmax3(accS[6], accS[7], accS[8]);
      float t3 = fmax3(accS[9], accS[10], accS[11]);
      float t4 = fmax3(accS[12], accS[13], accS[14]);
      pm = fmax3(fmax3(t0, t1, t2), fmax3(t3, t4, accS[15]),
                 __builtin_inff() * -1.0f);
      pm = fmaxf(pm, __shfl_xor(pm, 32));
    }

    // defer-max (T13): rescale only when some row max grows by > 8 (log2)
    if (__ballot(pm > m_ + 8.0f)) {
      const float mn = fmaxf(m_, pm);
      const float sc = exp2f(m_ - mn);
      m_ = mn;
      l_ *= sc;
      if (hi == 0) sW[wave][l31] = sc;
#pragma unroll
      for (int r = 0; r < 16; ++r) {
        const float scr = sW[wave][(r & 3) + 8 * (r >> 2) + 4 * hi];
#pragma unroll
        for (int db = 0; db < 4; ++db) accO[db][r] *= scr;
      }
    }

    // p = 2^(s - m); per-half row sum via binary tree (no per-tile shuffle)
    float sm[16];
#pragma unroll
    for (int j = 0; j < 16; ++j) {
      const float p = exp2f(accS[j] - m_);
      accS[j] = p;
      sm[j] = p;
    }
#pragma unroll
    for (int j = 0; j < 8; ++j) sm[j] += sm[j + 8];
#pragma unroll
    for (int j = 0; j < 4; ++j) sm[j] += sm[j + 4];
    l_ += (sm[0] + sm[1]) + (sm[2] + sm[3]);

    // pack P quads: pk[tq] covers k = 8*tq + 4*hi + {0..3}
    unsigned pk[4][2];
#pragma unroll
    for (int tq = 0; tq < 4; ++tq) {
      pk[tq][0] = pk2(accS[4 * tq + 0], accS[4 * tq + 1]);
      pk[tq][1] = pk2(accS[4 * tq + 2], accS[4 * tq + 3]);
    }

    // PV: 2 K=16 slices; A-frag via one lane-pair quad exchange per slice
    const __bf16* vt_ = sVt[cur];
#pragma unroll
    for (int kc = 0; kc < 2; ++kc) {
      const unsigned own0 = hi ? pk[2 * kc + 1][0] : pk[2 * kc][0];
      const unsigned own1 = hi ? pk[2 * kc + 1][1] : pk[2 * kc][1];
      const unsigned snd0 = hi ? pk[2 * kc][0] : pk[2 * kc + 1][0];
      const unsigned snd1 = hi ? pk[2 * kc][1] : pk[2 * kc + 1][1];
      const unsigned rc0 = (unsigned)__shfl_xor((int)snd0, 32);
      const unsigned rc1 = (unsigned)__shfl_xor((int)snd1, 32);
      u32x4 fr;
      fr[0] = hi ? rc0 : own0;
      fr[1] = hi ? rc1 : own1;
      fr[2] = hi ? own0 : rc0;
      fr[3] = hi ? own1 : rc1;
      const bf8_t pa = __builtin_bit_cast(bf8_t, fr);
#pragma unroll
      for (int db = 0; db < 4; ++db) {
        const int dr = db * 32 + l31;
        const int p = (kc * 2 + hi) ^ ((dr >> 1) & 3);
        bf8_t vb = *(const bf8_t*)&vt_[dr * 32 + p * 8];
        accO[db] = MFMA32(pa, vb, accO[db]);
      }
    }
  }

  // cross-half l reduce (once, not per tile)
  const float lf = l_ + __shfl_xor(l_, 32);

  // partial epilogue: unnormalized O (bf16) + (m,l) per q-row
  const size_t pbase = ((size_t)(z * 16 + bh) * 2048 + q0);
#pragma unroll
  for (int r = 0; r < 16; ++r) {
    const int qr = (r & 3) + 8 * (r >> 2) + 4 * hi;
    __bf16* op = Op + (pbase + qr) * 128 + l31;
#pragma unroll
    for (int db = 0; db < 4; ++db)
      op[db * 32] = (__bf16)(accO[db][r]);
  }
  if (hi == 0) {
    ml[(pbase + l31) * 2 + 0] = m_;
    ml[(pbase + l31) * 2 + 1] = lf;
  }
}

// ---------------------------------------------------------------------------
// Kernel 3b: merge the four KV-quarter partials.
// O = sum_i Oi*wi / sum_i li*wi, wi = 2^(mi - max_i mi).
// ---------------------------------------------------------------------------
__global__ __launch_bounds__(256) void attn_merge_k(
    const __bf16* __restrict__ Op, const float* __restrict__ ml,
    __bf16* __restrict__ Og) {
  const int bh = blockIdx.x >> 7, qc = blockIdx.x & 127;
  const int t = threadIdx.x;
  const int qr = qc * 16 + (t >> 4);
  const int d0 = (t & 15) * 8;
  const int b = bh >> 3, h = bh & 7;

  size_t idx[4];
  float mi[4], li[4];
  float m = -1e30f;
#pragma unroll
  for (int i = 0; i < 4; ++i) {
    idx[i] = ((size_t)(i * 16 + bh) * 2048 + qr);
    mi[i] = ml[idx[i] * 2];
    li[i] = ml[idx[i] * 2 + 1];
    m = fmaxf(m, mi[i]);
  }
  float den = 0.f, w[4];
#pragma unroll
  for (int i = 0; i < 4; ++i) {
    w[i] = exp2f(mi[i] - m);
    den += li[i] * w[i];
  }
  const float inv = 1.0f / den;

  float acc[8] = {0, 0, 0, 0, 0, 0, 0, 0};
#pragma unroll
  for (int i = 0; i < 4; ++i) {
    bf8_t o = *(const bf8_t*)(Op + idx[i] * 128 + d0);
#pragma unroll
    for (int j = 0; j < 8; ++j) acc[j] += (float)o[j] * w[i];
  }
  bf8_t r;
#pragma unroll
  for (int j = 0; j < 8; ++j) r[j] = (__bf16)(acc[j] * inv);
  *(bf8_t*)(Og + ((size_t)(b * 2048 + qr) * 1024) + h * 128 + d0) = r;
}

// ---------------------------------------------------------------------------
// Kernel 4: output projection + bias + LoRA-up. 64x128 tiles, 512 blocks.
// T1 XCD swizzle: xcd = lin&7 owns one Wo col-panel (L2-resident).
// Epilogue loads hoisted + vectorized (tmp as float4 per row, lup as float4).
// ---------------------------------------------------------------------------
__global__ __launch_bounds__(256) void gemm_out_k(
    const __bf16* __restrict__ A, const __bf16* __restrict__ Wo,
    const float* __restrict__ bo, const float* __restrict__ lup,
    const float* __restrict__ tmp, float* __restrict__ out) {
  __shared__ __bf16 sA[64 * 64];
  __shared__ __bf16 sB[128 * 64];
  const int lin = blockIdx.x + 8 * blockIdx.y;
  const int bcol = lin & 7;     // Wo panel = XCD owner
  const int brow = lin >> 3;    // 0..63
  const int K = 1024, N = 1024;
  f32x4 acc[2][4];
  gemm_tile<2>(A + (size_t)brow * 64 * K, Wo + (size_t)bcol * 128 * K, K, sA, sB, acc);

  const int lane = threadIdx.x & 63, wave = threadIdx.x >> 6;
  const int wr = (wave >> 1) * 32, wc = (wave & 1) * 64;

  // hoist per-row LoRA activations (one float4 each)
  float4 tv[2][4];
  int rows[2][4];
#pragma unroll
  for (int m = 0; m < 2; ++m)
#pragma unroll
    for (int j = 0; j < 4; ++j) {
      rows[m][j] = brow * 64 + wr + m * 16 + (lane >> 4) * 4 + j;
      tv[m][j] = *(const float4*)(tmp + rows[m][j] * 4);
    }

  for (int n = 0; n < 4; ++n) {
    const int col = bcol * 128 + wc + n * 16 + (lane & 15);
    const float bias = bo[col];
    const float4 u = *(const float4*)(lup + col * 4);
#pragma unroll
    for (int m = 0; m < 2; ++m)
#pragma unroll
      for (int j = 0; j < 4; ++j) {
        const float4 t = tv[m][j];
        float v = acc[m][n][j] + bias + t.x * u.x + t.y * u.y + t.z * u.z + t.w * u.w;
        out[(size_t)rows[m][j] * N + col] = v;
      }
  }
}

// ---------------------------------------------------------------------------
extern "C" void kernel_launch(void* const* d_in, const int* in_sizes, int n_in,
                              void* d_out, int out_size, void* d_ws, size_t ws_size,
                              hipStream_t stream) {
  (void)in_sizes; (void)n_in; (void)out_size; (void)ws_size;
  const float* hs  = (const float*)d_in[0];
  const float* cs  = (const float*)d_in[1];
  const float* Wq  = (const float*)d_in[2];
  const float* Wk  = (const float*)d_in[3];
  const float* Wv  = (const float*)d_in[4];
  const float* Wo  = (const float*)d_in[5];
  const float* bo  = (const float*)d_in[6];
  const float* ldw = (const float*)d_in[7];
  const float* lup = (const float*)d_in[8];
  float* out = (float*)d_out;

  const size_t MD = (size_t)4096 * 1024;   // B*S*D
  const size_t WD = (size_t)1024 * 1024;   // D*D
  __bf16* hsb = (__bf16*)d_ws;
  __bf16* Wqb = hsb + MD;
  __bf16* Wkb = Wqb + WD;
  __bf16* Wvb = Wkb + WD;
  __bf16* Wob = Wvb + WD;
  __bf16* Qb  = Wob + WD;
  __bf16* Kb  = Qb + MD;
  __bf16* Vtb = Kb + MD;   // V^T: [h*128+d][b*2048+s] = [1024][4096]
  __bf16* Ab  = Vtb + MD;
  float*  tmp = (float*)(Ab + MD);              // [4096][4]
  __bf16* Opart = (__bf16*)(tmp + 4096 * 4);    // [4][16][2048][128] bf16
  float*  mlp   = (float*)(Opart + (size_t)4 * 16 * 2048 * 128);  // [4][16][2048][2]

  cvt5_k<<<dim3(4096), 256, 0, stream>>>(hs, Wq, Wk, Wv, Wo,
                                         hsb, Wqb, Wkb, Wvb, Wob);
  gemm_qkv_k<<<dim3(8, 32, 3), 256, 0, stream>>>(hsb, Wqb, Wkb, Wvb, Qb, Kb, Vtb);
  lora_down_k<<<dim3(1024), 256, 0, stream>>>(cs, ldw, tmp);
  flash_attn_k<<<dim3(16, 16, 4), 256, 0, stream>>>(Qb, Kb, Vtb, Opart, mlp);
  attn_merge_k<<<dim3(2048), 256, 0, stream>>>(Opart, mlp, Ab);
  gemm_out_k<<<dim3(8, 64), 256, 0, stream>>>(Ab, Wob, bo, lup, tmp, out);
}